// Round 3
// baseline (181.840 us; speedup 1.0000x reference)
//
#include <hip/hip_runtime.h>
#include <hip/hip_bf16.h>

#define HID 1024
#define NH 8
#define HD 128
#define BB 2
#define SS 2048
#define CHK 128
#define NCH 16   // SS/CHK

typedef __attribute__((ext_vector_type(8))) short short8;
typedef __attribute__((ext_vector_type(4))) float f32x4;

static __device__ __forceinline__ float b2f(unsigned short u){
  unsigned int x = ((unsigned int)u) << 16; float f;
  __builtin_memcpy(&f, &x, 4); return f;
}
static __device__ __forceinline__ unsigned short f2b(float f){
  unsigned int x; __builtin_memcpy(&x, &f, 4);
  x += 0x7fffu + ((x >> 16) & 1u);
  return (unsigned short)(x >> 16);
}
static __device__ __forceinline__ float head_gamma(int h){
  double lo = -6.238324625039508;   // log(1/512)
  double hi = -3.4657359027997265;  // log(1/32)
  double lin = lo + (hi - lo) * ((double)h / 7.0);
  return (float)(1.0 - exp(lin));
}
static __device__ __forceinline__ f32x4 MFMA(short8 a, short8 b, f32x4 c){
  return __builtin_amdgcn_mfma_f32_16x16x32_bf16(a, b, c, 0, 0, 0);
}

// ---------------- fp32 -> bf16 convert (vectorized) ----------------
__global__ void k_cvt(const float* __restrict__ in, unsigned short* __restrict__ out, int n){
  int i = (blockIdx.x*blockDim.x + threadIdx.x)*4;
  int st = gridDim.x*blockDim.x*4;
  for (; i < n; i += st){
    float4 v = *(const float4*)(in + i);
    unsigned short o[4] = { f2b(v.x), f2b(v.y), f2b(v.z), f2b(v.w) };
    *(uint2*)(out + i) = *(const uint2*)o;
  }
}

// ---------------- fp32 [R][C] -> bf16 [C][R] transpose (batched) ----------------
__global__ __launch_bounds__(256) void k_wT(const float* __restrict__ in,
                                            unsigned short* __restrict__ out,
                                            int R, int C){
  __shared__ float tile[32][33];
  in  += (size_t)blockIdx.z * R * C;
  out += (size_t)blockIdx.z * R * C;
  int c0 = blockIdx.x*32, r0 = blockIdx.y*32;
  int tx = threadIdx.x & 31, ty = threadIdx.x >> 5;   // 32 x 8
  #pragma unroll
  for (int i=0;i<4;i++) tile[ty+i*8][tx] = in[(size_t)(r0+ty+i*8)*C + c0+tx];
  __syncthreads();
  #pragma unroll
  for (int i=0;i<4;i++) out[(size_t)(c0+ty+i*8)*R + r0+tx] = f2b(tile[tx][ty+i*8]);
}

// ---------------- qkv projection: per head, bf16 MFMA, no LDS ----------------
__global__ __launch_bounds__(256) void k_qkv(
    const unsigned short* __restrict__ xb,     // [B*S][1024]
    const unsigned short* __restrict__ wqT,    // [H][e=128][d=128]
    const unsigned short* __restrict__ wkT,
    const unsigned short* __restrict__ wvT,
    unsigned short* __restrict__ qb,           // [B][H][S][128]
    unsigned short* __restrict__ kb,
    unsigned short* __restrict__ vb)
{
  int bid = blockIdx.x;            // (b*8+h)*32 + stile
  int stile = bid & 31;
  int bh = bid >> 5;
  int h = bh & 7, b = bh >> 3;
  int t = threadIdx.x, wv = t>>6, l = t&63, lr = l&15, lg = l>>4;
  int row0 = stile*64 + wv*16;
  short8 a[4];
  const unsigned short* xp = xb + (size_t)(b*SS + row0 + lr)*HID + h*HD + lg*8;
  #pragma unroll
  for (int kk=0;kk<4;kk++) a[kk] = *(const short8*)(xp + kk*32);
  size_t obase = ((size_t)bh*SS + row0)*HD;
  const unsigned short* wts[3] = { wqT + (size_t)h*HD*HD, wkT + (size_t)h*HD*HD, wvT + (size_t)h*HD*HD };
  unsigned short* outs[3]      = { qb + obase, kb + obase, vb + obase };
  for (int m=0;m<3;m++){
    const unsigned short* wb = wts[m];
    unsigned short* op = outs[m];
    #pragma unroll
    for (int nt=0;nt<8;nt++){
      f32x4 acc = {0.f,0.f,0.f,0.f};
      #pragma unroll
      for (int kk=0;kk<4;kk++){
        short8 bfr = *(const short8*)(wb + (size_t)(nt*16+lr)*HD + kk*32 + lg*8);
        acc = MFMA(a[kk], bfr, acc);
      }
      #pragma unroll
      for (int r=0;r<4;r++)
        op[(size_t)(lg*4+r)*HD + nt*16 + lr] = f2b(acc[r]);
    }
  }
}

// ---------------- per-chunk KV summary (TRANSPOSED OUTPUT):
//   U[e][d] = sum_m gamma^{127-m} v[m][e] k[m][d]  ----------------
__global__ __launch_bounds__(256) void k_chunksum(
    const unsigned short* __restrict__ kb,
    const unsigned short* __restrict__ vb,
    float* __restrict__ U)                    // [B*H*16][e=128][d=128]
{
  int bid = blockIdx.x;                       // bh*16 + c
  int c = bid & 15, bh = bid >> 4, h = bh & 7;
  float g = head_gamma(h);
  float l2g = log2f(g);
  __shared__ unsigned short kT[HD][72];
  __shared__ unsigned short vT[HD][72];
  int t = threadIdx.x, wv = t>>6, l = t&63, lr = l&15, lg = l>>4;
  const unsigned short* kc = kb + ((size_t)bh*SS + c*CHK)*HD;
  const unsigned short* vc = vb + ((size_t)bh*SS + c*CHK)*HD;
  f32x4 acc[2][8];
  #pragma unroll
  for (int i=0;i<2;i++)
    #pragma unroll
    for (int j=0;j<8;j++) acc[i][j] = (f32x4){0.f,0.f,0.f,0.f};
  for (int half=0; half<2; half++){
    if (half) __syncthreads();
    #pragma unroll
    for (int it=0; it<4; it++){
      int cid = t + it*256;
      int m = cid >> 4;
      int dc = (cid & 15)*8;
      int mg = half*64 + m;
      short8 kv = *(const short8*)(kc + (size_t)mg*HD + dc);
      short8 vv = *(const short8*)(vc + (size_t)mg*HD + dc);
      float ks = exp2f((float)(CHK-1-mg)*l2g);
      #pragma unroll
      for (int e=0;e<8;e++){
        kT[dc+e][m] = f2b(b2f((unsigned short)kv[e]) * ks);
        vT[dc+e][m] = (unsigned short)vv[e];
      }
    }
    __syncthreads();
    #pragma unroll
    for (int ks=0; ks<2; ks++){
      short8 bfr[8];
      #pragma unroll
      for (int nt=0;nt<8;nt++) bfr[nt] = *(const short8*)&kT[nt*16+lr][ks*32+lg*8];
      #pragma unroll
      for (int mt=0;mt<2;mt++){
        short8 afr = *(const short8*)&vT[wv*32+mt*16+lr][ks*32+lg*8];
        #pragma unroll
        for (int nt=0;nt<8;nt++)
          acc[mt][nt] = MFMA(afr, bfr[nt], acc[mt][nt]);
      }
    }
  }
  float* Up = U + (size_t)bid*HD*HD;
  #pragma unroll
  for (int mt=0;mt<2;mt++)
    #pragma unroll
    for (int nt=0;nt<8;nt++)
      #pragma unroll
      for (int r=0;r<4;r++)
        Up[(size_t)(wv*32+mt*16+lg*4+r)*HD + nt*16+lr] = acc[mt][nt][r];
}

// ---------------- cross-chunk state scan: S_0 = 0; S_j = g^128 * S_{j-1} + U[j-1] ----------------
__global__ __launch_bounds__(256) void k_state(
    const float* __restrict__ U,              // [B*H][16][128*128] ([e][d])
    unsigned short* __restrict__ ST)          // [B*H][16][128*128] ([e][d])
{
  int bid = blockIdx.x;                       // bh*64 + eb
  int eb = bid & 63, bh = bid >> 6, h = bh & 7;
  float g = head_gamma(h);
  float d128 = exp2f(128.f * log2f(g));       // gamma^128
  int idx = eb*256 + threadIdx.x;
  const float* Ub = U + (size_t)bh*NCH*HD*HD + idx;
  unsigned short* Sb = ST + (size_t)bh*NCH*HD*HD + idx;
  float s = 0.f;
  #pragma unroll
  for (int c=0;c<NCH;c++){
    Sb[(size_t)c*HD*HD] = f2b(s);
    s = s*d128 + Ub[(size_t)c*HD*HD];
  }
}

// ---------------- retention core: 64 rows of one chunk per block + GroupNorm ----------------
__global__ __launch_bounds__(256) void k_ret(
    const unsigned short* __restrict__ qb,
    const unsigned short* __restrict__ kb,
    const unsigned short* __restrict__ vb,
    const unsigned short* __restrict__ ST,   // [B*H*16][e][d]
    const float* __restrict__ gnw,
    const float* __restrict__ gnb,
    float* __restrict__ ret)                 // [B*S][1024]
{
  int bid = blockIdx.x;                      // ((bh*16 + j)*2 + rh)
  int rh = bid & 1;
  int cj = bid >> 1;
  int j = cj & 15, bh = cj >> 4, h = bh & 7, b = bh >> 3;
  int p = j*CHK;
  int rbase = rh*64;                         // this block's rows within the chunk
  float g = head_gamma(h);
  float l2g = log2f(g);
  __shared__ unsigned short sc[64][136];
  __shared__ unsigned short vT[HD][72];
  __shared__ float gpow[CHK];
  int t = threadIdx.x, wv = t>>6, l = t&63, lr = l&15, lg = l>>4;
  if (t < CHK) gpow[t] = exp2f((float)t * l2g);
  const unsigned short* qc = qb + ((size_t)bh*SS + p)*HD;
  const unsigned short* kc = kb + ((size_t)bh*SS + p)*HD;
  const unsigned short* vc = vb + ((size_t)bh*SS + p)*HD;
  const unsigned short* Sp = ST + (size_t)cj*HD*HD;
  __syncthreads();

  auto stageV = [&](int half){
    #pragma unroll
    for (int it=0; it<4; it++){
      int cid = t + it*256;
      int m = cid >> 4;
      int dc = (cid & 15)*8;
      short8 vv = *(const short8*)(vc + (size_t)(half*64 + m)*HD + dc);
      #pragma unroll
      for (int e=0;e<8;e++) vT[dc+e][m] = (unsigned short)vv[e];
    }
  };

  // q fragments: this wave's 16 rows (4 k-steps)
  short8 qf[4];
  #pragma unroll
  for (int kk=0;kk<4;kk++)
    qf[kk] = *(const short8*)(qc + (size_t)(rbase + wv*16 + lr)*HD + kk*32 + lg*8);

  // Phase A: scores = (q k^T) * decay mask -> sc (bf16)
  #pragma unroll
  for (int nt=0;nt<8;nt++){
    f32x4 a0 = {0,0,0,0};
    #pragma unroll
    for (int kk=0;kk<4;kk++){
      short8 bfr = *(const short8*)(kc + (size_t)(nt*16+lr)*HD + kk*32 + lg*8);
      a0 = MFMA(qf[kk], bfr, a0);
    }
    int col = nt*16 + lr;
    #pragma unroll
    for (int r=0;r<4;r++){
      int lrow = wv*16 + lg*4 + r;        // row within this block's 64
      int n = rbase + lrow;               // row within chunk
      float v0 = (col <= n) ? a0[r]*gpow[n-col] : 0.f;
      sc[lrow][col] = f2b(v0);
    }
  }
  stageV(0);

  // Phase B: acc = gamma^{row+1} * (q @ S)
  f32x4 acc[8];
  #pragma unroll
  for (int nt=0;nt<8;nt++){
    f32x4 a = {0,0,0,0};
    #pragma unroll
    for (int kk=0;kk<4;kk++){
      short8 bfr = *(const short8*)(Sp + (size_t)(nt*16+lr)*HD + kk*32 + lg*8);
      a = MFMA(qf[kk], bfr, a);
    }
    acc[nt] = a;
  }
  #pragma unroll
  for (int r=0;r<4;r++){
    int n = rbase + wv*16 + lg*4 + r;
    float sf = gpow[n]*g;                 // gamma^{n+1}
    #pragma unroll
    for (int nt=0;nt<8;nt++) acc[nt][r] *= sf;
  }
  __syncthreads();

  // += intra-chunk scores @ v (two 64-position halves)
  for (int half=0; half<2; half++){
    if (half){ __syncthreads(); stageV(1); __syncthreads(); }
    #pragma unroll
    for (int ks=0; ks<2; ks++){
      short8 bfr[8];
      #pragma unroll
      for (int nt=0;nt<8;nt++) bfr[nt] = *(const short8*)&vT[nt*16+lr][ks*32+lg*8];
      short8 afr = *(const short8*)&sc[wv*16+lr][half*64 + ks*32 + lg*8];
      #pragma unroll
      for (int nt=0;nt<8;nt++)
        acc[nt] = MFMA(afr, bfr[nt], acc[nt]);
    }
  }

  // Epilogue: GroupNorm over d=128 per row, scale/shift, store fp32
  float* rp = ret + ((size_t)(b*SS + p + rbase))*HID + h*HD;
  const float* gw  = gnw + h*HD;
  const float* gbb = gnb + h*HD;
  #pragma unroll
  for (int r=0;r<4;r++){
    float s = 0.f, ss = 0.f;
    #pragma unroll
    for (int nt=0;nt<8;nt++){ float x = acc[nt][r]; s += x; ss += x*x; }
    #pragma unroll
    for (int off=1; off<16; off<<=1){
      s  += __shfl_xor(s,  off, 64);
      ss += __shfl_xor(ss, off, 64);
    }
    float mu  = s*(1.f/128.f);
    float var = ss*(1.f/128.f) - mu*mu;
    float rs  = rsqrtf(var + 1e-5f);
    int lrow = wv*16 + lg*4 + r;
    float* orow = rp + (size_t)lrow*HID;
    #pragma unroll
    for (int nt=0;nt<8;nt++){
      int col = nt*16 + lr;
      orow[col] = (acc[nt][r]-mu)*rs*gw[col] + gbb[col];
    }
  }
}

// ---------------- 64x128-tile bf16 GEMM (B^T input), epilogue variants ----------------
// EPI==1: Cb = bf16( swish(C) + radd )   EPI==2: Cf = C (fp32)
template<int EPI>
__global__ __launch_bounds__(256) void k_gemm(
    const unsigned short* __restrict__ A,    // [M][K]
    const unsigned short* __restrict__ BT,   // [N][K]
    const float* __restrict__ radd,
    unsigned short* __restrict__ Cb,
    float* __restrict__ Cf,
    int M, int N, int K)
{
  __shared__ unsigned short la[64][72];
  __shared__ unsigned short lb[128][72];
  int nb = N >> 7;
  int m0 = (blockIdx.x / nb) << 6;
  int n0 = (blockIdx.x % nb) << 7;
  int t = threadIdx.x, wv=t>>6, l=t&63, lr=l&15, lg=l>>4;
  int wr = (wv>>1)<<5;        // 0 or 32
  int wc = (wv&1)<<6;         // 0 or 64
  f32x4 acc[2][4];
  #pragma unroll
  for (int i=0;i<2;i++)
    #pragma unroll
    for (int jx=0;jx<4;jx++) acc[i][jx] = (f32x4){0,0,0,0};
  for (int k0=0; k0<K; k0+=64){
    if (k0) __syncthreads();
    #pragma unroll
    for (int it=0; it<2; it++){
      int cid = t + it*256;
      int row = cid>>3, kc=(cid&7)*8;
      *(short8*)&la[row][kc] = *(const short8*)(A + (size_t)(m0+row)*K + k0+kc);
    }
    #pragma unroll
    for (int it=0; it<4; it++){
      int cid = t + it*256;
      int row = cid>>3, kc=(cid&7)*8;
      *(short8*)&lb[row][kc] = *(const short8*)(BT + (size_t)(n0+row)*K + k0+kc);
    }
    __syncthreads();
    #pragma unroll
    for (int ks=0; ks<2; ks++){
      short8 af[2], bf[4];
      #pragma unroll
      for (int i=0;i<2;i++) af[i] = *(const short8*)&la[wr+i*16+lr][ks*32+lg*8];
      #pragma unroll
      for (int jx=0;jx<4;jx++) bf[jx] = *(const short8*)&lb[wc+jx*16+lr][ks*32+lg*8];
      #pragma unroll
      for (int i=0;i<2;i++)
        #pragma unroll
        for (int jx=0;jx<4;jx++)
          acc[i][jx] = MFMA(af[i], bf[jx], acc[i][jx]);
    }
  }
  #pragma unroll
  for (int i=0;i<2;i++){
    #pragma unroll
    for (int jx=0;jx<4;jx++){
      #pragma unroll
      for (int r=0;r<4;r++){
        int row = m0 + wr + i*16 + lg*4 + r;
        int col = n0 + wc + jx*16 + lr;
        float v = acc[i][jx][r];
        if (EPI == 1){
          float sw = v / (1.f + __expf(-v));
          Cb[(size_t)row*N + col] = f2b(sw + radd[(size_t)row*N + col]);
        } else {
          Cf[(size_t)row*N + col] = v;
        }
      }
    }
  }
}

extern "C" void kernel_launch(void* const* d_in, const int* in_sizes, int n_in,
                              void* d_out, int out_size, void* d_ws, size_t ws_size,
                              hipStream_t stream)
{
  (void)in_sizes; (void)n_in; (void)out_size; (void)ws_size;
  const float* x   = (const float*)d_in[0];
  const float* Wq  = (const float*)d_in[1];
  const float* Wk  = (const float*)d_in[2];
  const float* Wv  = (const float*)d_in[3];
  const float* W1  = (const float*)d_in[4];
  const float* W2  = (const float*)d_in[5];
  const float* gnw = (const float*)d_in[6];
  const float* gnb = (const float*)d_in[7];
  float* out = (float*)d_out;

  char* wsp = (char*)d_ws;
  size_t off = 0;
  auto alloc = [&](size_t bytes)->void*{
    off = (off + 255) & ~(size_t)255;
    void* p = wsp + off; off += bytes; return p;
  };
  const size_t NTOK = (size_t)BB*SS;  // 4096
  unsigned short* xb  = (unsigned short*)alloc(NTOK*HID*2);
  unsigned short* w1T = (unsigned short*)alloc((size_t)HID*HID*2);
  unsigned short* w2T = (unsigned short*)alloc((size_t)HID*HID*2);
  unsigned short* wqT = (unsigned short*)alloc((size_t)NH*HD*HD*2);
  unsigned short* wkT = (unsigned short*)alloc((size_t)NH*HD*HD*2);
  unsigned short* wvT = (unsigned short*)alloc((size_t)NH*HD*HD*2);
  unsigned short* qb  = (unsigned short*)alloc(NTOK*HID*2);
  unsigned short* kb  = (unsigned short*)alloc(NTOK*HID*2);
  unsigned short* vb  = (unsigned short*)alloc(NTOK*HID*2);
  float*          U   = (float*)alloc((size_t)BB*NH*NCH*HD*HD*4);
  unsigned short* ST  = (unsigned short*)alloc((size_t)BB*NH*NCH*HD*HD*2);
  float*          rtb = (float*)alloc(NTOK*HID*4);
  unsigned short* opb = (unsigned short*)alloc(NTOK*HID*2);

  k_cvt<<<dim3(1024), dim3(256), 0, stream>>>(x, xb, (int)(NTOK*HID));
  k_wT<<<dim3(32,32,1), dim3(256), 0, stream>>>(W1, w1T, HID, HID);
  k_wT<<<dim3(32,32,1), dim3(256), 0, stream>>>(W2, w2T, HID, HID);
  k_wT<<<dim3(4,4,NH), dim3(256), 0, stream>>>(Wq, wqT, HD, HD);
  k_wT<<<dim3(4,4,NH), dim3(256), 0, stream>>>(Wk, wkT, HD, HD);
  k_wT<<<dim3(4,4,NH), dim3(256), 0, stream>>>(Wv, wvT, HD, HD);

  k_qkv<<<dim3(BB*NH*32), dim3(256), 0, stream>>>(xb, wqT, wkT, wvT, qb, kb, vb);
  k_chunksum<<<dim3(BB*NH*NCH), dim3(256), 0, stream>>>(kb, vb, U);
  k_state<<<dim3(BB*NH*64), dim3(256), 0, stream>>>(U, ST);
  k_ret<<<dim3(BB*NH*NCH*2), dim3(256), 0, stream>>>(qb, kb, vb, ST, gnw, gnb, rtb);

  k_gemm<1><<<dim3(512), dim3(256), 0, stream>>>(xb,  w1T, rtb, opb, nullptr, (int)NTOK, HID, HID);
  k_gemm<2><<<dim3(512), dim3(256), 0, stream>>>(opb, w2T, nullptr, nullptr, out, (int)NTOK, HID, HID);
}

// Round 4
// 122.539 us; speedup vs baseline: 1.4839x; 1.4839x over previous
//
#include <hip/hip_runtime.h>
#include <hip/hip_bf16.h>

#define HID 1024
#define NH 8
#define HD 128
#define BB 2
#define SS 2048
#define CHK 128
#define NCH 16   // SS/CHK

typedef __attribute__((ext_vector_type(8))) short short8;
typedef __attribute__((ext_vector_type(4))) float f32x4;

static __device__ __forceinline__ float b2f(unsigned short u){
  unsigned int x = ((unsigned int)u) << 16; float f;
  __builtin_memcpy(&f, &x, 4); return f;
}
static __device__ __forceinline__ unsigned short f2b(float f){
  unsigned int x; __builtin_memcpy(&x, &f, 4);
  x += 0x7fffu + ((x >> 16) & 1u);
  return (unsigned short)(x >> 16);
}
static __device__ __forceinline__ float head_gamma(int h){
  double lo = -6.238324625039508;   // log(1/512)
  double hi = -3.4657359027997265;  // log(1/32)
  double lin = lo + (hi - lo) * ((double)h / 7.0);
  return (float)(1.0 - exp(lin));
}
static __device__ __forceinline__ f32x4 MFMA(short8 a, short8 b, f32x4 c){
  return __builtin_amdgcn_mfma_f32_16x16x32_bf16(a, b, c, 0, 0, 0);
}

typedef const __attribute__((address_space(1))) unsigned int* gas1_u32p;
typedef __attribute__((address_space(3))) unsigned int* las3_u32p;
static __device__ __forceinline__ void gload_lds16(const void* g, void* l){
  __builtin_amdgcn_global_load_lds((gas1_u32p)g, (las3_u32p)l, 16, 0, 0);
}

// ---------------- fp32 -> bf16 convert (vectorized) ----------------
__global__ void k_cvt(const float* __restrict__ in, unsigned short* __restrict__ out, int n){
  int i = (blockIdx.x*blockDim.x + threadIdx.x)*4;
  int st = gridDim.x*blockDim.x*4;
  for (; i < n; i += st){
    float4 v = *(const float4*)(in + i);
    unsigned short o[4] = { f2b(v.x), f2b(v.y), f2b(v.z), f2b(v.w) };
    *(uint2*)(out + i) = *(const uint2*)o;
  }
}

// ---------------- fp32 [R][C] -> bf16 [C][R] transpose (batched) ----------------
__global__ __launch_bounds__(256) void k_wT(const float* __restrict__ in,
                                            unsigned short* __restrict__ out,
                                            int R, int C){
  __shared__ float tile[32][33];
  in  += (size_t)blockIdx.z * R * C;
  out += (size_t)blockIdx.z * R * C;
  int c0 = blockIdx.x*32, r0 = blockIdx.y*32;
  int tx = threadIdx.x & 31, ty = threadIdx.x >> 5;   // 32 x 8
  #pragma unroll
  for (int i=0;i<4;i++) tile[ty+i*8][tx] = in[(size_t)(r0+ty+i*8)*C + c0+tx];
  __syncthreads();
  #pragma unroll
  for (int i=0;i<4;i++) out[(size_t)(c0+ty+i*8)*R + r0+tx] = f2b(tile[tx][ty+i*8]);
}

// ---------------- qkv projection: per head, bf16 MFMA, no LDS ----------------
__global__ __launch_bounds__(256) void k_qkv(
    const unsigned short* __restrict__ xb,     // [B*S][1024]
    const unsigned short* __restrict__ wqT,    // [H][e=128][d=128]
    const unsigned short* __restrict__ wkT,
    const unsigned short* __restrict__ wvT,
    unsigned short* __restrict__ qb,           // [B][H][S][128]
    unsigned short* __restrict__ kb,
    unsigned short* __restrict__ vb)
{
  int bid = blockIdx.x;            // (b*8+h)*32 + stile
  int stile = bid & 31;
  int bh = bid >> 5;
  int h = bh & 7, b = bh >> 3;
  int t = threadIdx.x, wv = t>>6, l = t&63, lr = l&15, lg = l>>4;
  int row0 = stile*64 + wv*16;
  short8 a[4];
  const unsigned short* xp = xb + (size_t)(b*SS + row0 + lr)*HID + h*HD + lg*8;
  #pragma unroll
  for (int kk=0;kk<4;kk++) a[kk] = *(const short8*)(xp + kk*32);
  size_t obase = ((size_t)bh*SS + row0)*HD;
  const unsigned short* wts[3] = { wqT + (size_t)h*HD*HD, wkT + (size_t)h*HD*HD, wvT + (size_t)h*HD*HD };
  unsigned short* outs[3]      = { qb + obase, kb + obase, vb + obase };
  for (int m=0;m<3;m++){
    const unsigned short* wb = wts[m];
    unsigned short* op = outs[m];
    #pragma unroll
    for (int nt=0;nt<8;nt++){
      f32x4 acc = {0.f,0.f,0.f,0.f};
      #pragma unroll
      for (int kk=0;kk<4;kk++){
        short8 bfr = *(const short8*)(wb + (size_t)(nt*16+lr)*HD + kk*32 + lg*8);
        acc = MFMA(a[kk], bfr, acc);
      }
      #pragma unroll
      for (int r=0;r<4;r++)
        op[(size_t)(lg*4+r)*HD + nt*16 + lr] = f2b(acc[r]);
    }
  }
}

// ---------------- per-chunk KV summary (TRANSPOSED OUTPUT):
//   U[e][d] = sum_m gamma^{127-m} v[m][e] k[m][d]  ----------------
__global__ __launch_bounds__(256) void k_chunksum(
    const unsigned short* __restrict__ kb,
    const unsigned short* __restrict__ vb,
    float* __restrict__ U)                    // [B*H*16][e=128][d=128]
{
  int bid = blockIdx.x;                       // bh*16 + c
  int c = bid & 15, bh = bid >> 4, h = bh & 7;
  float g = head_gamma(h);
  float l2g = log2f(g);
  __shared__ unsigned short kT[HD][72];
  __shared__ unsigned short vT[HD][72];
  int t = threadIdx.x, wv = t>>6, l = t&63, lr = l&15, lg = l>>4;
  const unsigned short* kc = kb + ((size_t)bh*SS + c*CHK)*HD;
  const unsigned short* vc = vb + ((size_t)bh*SS + c*CHK)*HD;
  f32x4 acc[2][8];
  #pragma unroll
  for (int i=0;i<2;i++)
    #pragma unroll
    for (int j=0;j<8;j++) acc[i][j] = (f32x4){0.f,0.f,0.f,0.f};
  for (int half=0; half<2; half++){
    if (half) __syncthreads();
    #pragma unroll
    for (int it=0; it<4; it++){
      int cid = t + it*256;
      int m = cid >> 4;
      int dc = (cid & 15)*8;
      int mg = half*64 + m;
      short8 kv = *(const short8*)(kc + (size_t)mg*HD + dc);
      short8 vv = *(const short8*)(vc + (size_t)mg*HD + dc);
      float ks = exp2f((float)(CHK-1-mg)*l2g);
      #pragma unroll
      for (int e=0;e<8;e++){
        kT[dc+e][m] = f2b(b2f((unsigned short)kv[e]) * ks);
        vT[dc+e][m] = (unsigned short)vv[e];
      }
    }
    __syncthreads();
    #pragma unroll
    for (int ks=0; ks<2; ks++){
      short8 bfr[8];
      #pragma unroll
      for (int nt=0;nt<8;nt++) bfr[nt] = *(const short8*)&kT[nt*16+lr][ks*32+lg*8];
      #pragma unroll
      for (int mt=0;mt<2;mt++){
        short8 afr = *(const short8*)&vT[wv*32+mt*16+lr][ks*32+lg*8];
        #pragma unroll
        for (int nt=0;nt<8;nt++)
          acc[mt][nt] = MFMA(afr, bfr[nt], acc[mt][nt]);
      }
    }
  }
  float* Up = U + (size_t)bid*HD*HD;
  #pragma unroll
  for (int mt=0;mt<2;mt++)
    #pragma unroll
    for (int nt=0;nt<8;nt++)
      #pragma unroll
      for (int r=0;r<4;r++)
        Up[(size_t)(wv*32+mt*16+lg*4+r)*HD + nt*16+lr] = acc[mt][nt][r];
}

// ---------------- cross-chunk state scan: S_0 = 0; S_j = g^128 * S_{j-1} + U[j-1] ----------------
__global__ __launch_bounds__(256) void k_state(
    const float* __restrict__ U,              // [B*H][16][128*128] ([e][d])
    unsigned short* __restrict__ ST)          // [B*H][16][128*128] ([e][d])
{
  int bid = blockIdx.x;                       // bh*64 + eb
  int eb = bid & 63, bh = bid >> 6, h = bh & 7;
  float g = head_gamma(h);
  float d128 = exp2f(128.f * log2f(g));       // gamma^128
  int idx = eb*256 + threadIdx.x;
  const float* Ub = U + (size_t)bh*NCH*HD*HD + idx;
  unsigned short* Sb = ST + (size_t)bh*NCH*HD*HD + idx;
  float s = 0.f;
  #pragma unroll
  for (int c=0;c<NCH;c++){
    Sb[(size_t)c*HD*HD] = f2b(s);
    s = s*d128 + Ub[(size_t)c*HD*HD];
  }
}

// ---------------- retention core per chunk + GroupNorm (bf16 output) ----------------
__global__ __launch_bounds__(256) void k_ret(
    const unsigned short* __restrict__ qb,
    const unsigned short* __restrict__ kb,
    const unsigned short* __restrict__ vb,
    const unsigned short* __restrict__ ST,   // [B*H*16][e][d]
    const float* __restrict__ gnw,
    const float* __restrict__ gnb,
    unsigned short* __restrict__ ret)        // bf16 [B*S][1024]
{
  int bid = blockIdx.x;                      // bh*16 + j
  int j = bid & 15, bh = bid >> 4, h = bh & 7, b = bh >> 3;
  int p = j*CHK;
  float g = head_gamma(h);
  float l2g = log2f(g);
  __shared__ unsigned short sc[CHK][136];
  __shared__ unsigned short vT[HD][72];
  __shared__ float gpow[CHK];
  int t = threadIdx.x, wv = t>>6, l = t&63, lr = l&15, lg = l>>4;
  if (t < CHK) gpow[t] = exp2f((float)t * l2g);
  const unsigned short* qc = qb + ((size_t)bh*SS + p)*HD;
  const unsigned short* kc = kb + ((size_t)bh*SS + p)*HD;
  const unsigned short* vc = vb + ((size_t)bh*SS + p)*HD;
  const unsigned short* Sp = ST + (size_t)bid*HD*HD;
  __syncthreads();

  auto stageV = [&](int half){
    #pragma unroll
    for (int it=0; it<4; it++){
      int cid = t + it*256;
      int m = cid >> 4;
      int dc = (cid & 15)*8;
      short8 vv = *(const short8*)(vc + (size_t)(half*64 + m)*HD + dc);
      #pragma unroll
      for (int e=0;e<8;e++) vT[dc+e][m] = (unsigned short)vv[e];
    }
  };

  // q fragments for this wave's 32 rows (2 row-tiles x 4 k-steps)
  short8 qf[2][4];
  #pragma unroll
  for (int mt=0;mt<2;mt++)
    #pragma unroll
    for (int kk=0;kk<4;kk++)
      qf[mt][kk] = *(const short8*)(qc + (size_t)(wv*32+mt*16+lr)*HD + kk*32 + lg*8);

  // Phase A: scores = (q k^T) * decay mask -> sc (bf16)
  #pragma unroll
  for (int nt=0;nt<8;nt++){
    f32x4 a0 = {0,0,0,0}, a1 = {0,0,0,0};
    #pragma unroll
    for (int kk=0;kk<4;kk++){
      short8 bfr = *(const short8*)(kc + (size_t)(nt*16+lr)*HD + kk*32 + lg*8);
      a0 = MFMA(qf[0][kk], bfr, a0);
      a1 = MFMA(qf[1][kk], bfr, a1);
    }
    int col = nt*16 + lr;
    #pragma unroll
    for (int r=0;r<4;r++){
      int r0 = wv*32 + lg*4 + r;
      int r1 = r0 + 16;
      float v0 = (col <= r0) ? a0[r]*gpow[r0-col] : 0.f;
      float v1 = (col <= r1) ? a1[r]*gpow[r1-col] : 0.f;
      sc[r0][col] = f2b(v0);
      sc[r1][col] = f2b(v1);
    }
  }
  stageV(0);
  __syncthreads();

  // Phase B: acc = gamma^{row+1} * (q @ S)  then += intra-chunk scores @ v
  f32x4 acc[2][8];
  #pragma unroll
  for (int mt=0;mt<2;mt++)
    #pragma unroll
    for (int nt=0;nt<8;nt++){
      f32x4 a = {0,0,0,0};
      #pragma unroll
      for (int kk=0;kk<4;kk++){
        short8 bfr = *(const short8*)(Sp + (size_t)(nt*16+lr)*HD + kk*32 + lg*8);
        a = MFMA(qf[mt][kk], bfr, a);
      }
      acc[mt][nt] = a;
    }
  #pragma unroll
  for (int mt=0;mt<2;mt++)
    #pragma unroll
    for (int r=0;r<4;r++){
      int rr = wv*32 + mt*16 + lg*4 + r;
      float sf = gpow[rr]*g;
      #pragma unroll
      for (int nt=0;nt<8;nt++) acc[mt][nt][r] *= sf;
    }

  for (int half=0; half<2; half++){
    if (half){ __syncthreads(); stageV(1); __syncthreads(); }
    #pragma unroll
    for (int ks=0; ks<2; ks++){
      short8 bfr[8];
      #pragma unroll
      for (int nt=0;nt<8;nt++) bfr[nt] = *(const short8*)&vT[nt*16+lr][ks*32+lg*8];
      #pragma unroll
      for (int mt=0;mt<2;mt++){
        short8 afr = *(const short8*)&sc[wv*32+mt*16+lr][half*64 + ks*32 + lg*8];
        #pragma unroll
        for (int nt=0;nt<8;nt++)
          acc[mt][nt] = MFMA(afr, bfr[nt], acc[mt][nt]);
      }
    }
  }

  // Epilogue: GroupNorm over d=128 per row, scale/shift, store bf16
  unsigned short* rp = ret + ((size_t)(b*SS + p))*HID + h*HD;
  const float* gw  = gnw + h*HD;
  const float* gbb = gnb + h*HD;
  #pragma unroll
  for (int mt=0;mt<2;mt++){
    #pragma unroll
    for (int r=0;r<4;r++){
      float s = 0.f, ss = 0.f;
      #pragma unroll
      for (int nt=0;nt<8;nt++){ float x = acc[mt][nt][r]; s += x; ss += x*x; }
      #pragma unroll
      for (int off=1; off<16; off<<=1){
        s  += __shfl_xor(s,  off, 64);
        ss += __shfl_xor(ss, off, 64);
      }
      float mu  = s*(1.f/128.f);
      float var = ss*(1.f/128.f) - mu*mu;
      float rs  = rsqrtf(var + 1e-5f);
      int rr = wv*32 + mt*16 + lg*4 + r;
      unsigned short* orow = rp + (size_t)rr*HID;
      #pragma unroll
      for (int nt=0;nt<8;nt++){
        int col = nt*16 + lr;
        orow[col] = f2b((acc[mt][nt][r]-mu)*rs*gw[col] + gbb[col]);
      }
    }
  }
}

// ---------------- 128x128-tile bf16 GEMM, global_load_lds + dbuf + T2 swizzle ----------------
// 512 threads, 8 waves (32x64 sub-tile each). BK=64.
// LDS layout: linear [row][64] shorts, physically col-block p holds logical block p^(row&7).
// EPI==1: Cb = bf16( swish(C) + bf16 radd )   EPI==2: Cf = C (fp32)
template<int EPI>
__global__ __launch_bounds__(512) void k_gemm(
    const unsigned short* __restrict__ A,    // [M][K]
    const unsigned short* __restrict__ BT,   // [N][K]
    const unsigned short* __restrict__ radd, // bf16 [M][N] (EPI==1)
    unsigned short* __restrict__ Cb,
    float* __restrict__ Cf,
    int M, int N, int K)
{
  __shared__ unsigned short ls[2][2][128*64];   // [buf][A/B][row*64+col] = 64 KiB
  const int nb = N >> 7;
  const int m0 = (int)(blockIdx.x / nb) << 7;
  const int n0 = (int)(blockIdx.x % nb) << 7;
  const int t = threadIdx.x, wv = t>>6, l = t&63, lr = l&15, lg = l>>4;
  const int wr = (wv>>1)<<5;     // 0,32,64,96
  const int wc = (wv&1)<<6;      // 0,64
  // staging geometry: wave wv stages rows [wv*16, wv*16+16) of A and of BT.
  // gload_lds writes lds_base + lane*16B: lane l -> row +(l>>3), phys colblock (l&7).
  // swizzle: phys block p at row r holds logical block p^(r&7); r&7 == (l>>3)&7 == l>>3.
  const int srow = l >> 3;                   // 0..7
  const int sgc  = ((l & 7) ^ srow) << 3;    // source col offset (shorts)
  const unsigned short* Abase = A  + (size_t)(m0 + wv*16 + srow)*K + sgc;
  const unsigned short* Bbase = BT + (size_t)(n0 + wv*16 + srow)*K + sgc;

  auto stage = [&](int buf, int k0){
    unsigned short* la = &ls[buf][0][0];
    unsigned short* lb = &ls[buf][1][0];
    #pragma unroll
    for (int it=0; it<2; ++it){
      gload_lds16(Abase + (size_t)(it*8)*K + k0, la + (wv*16 + it*8)*64);
      gload_lds16(Bbase + (size_t)(it*8)*K + k0, lb + (wv*16 + it*8)*64);
    }
  };

  f32x4 acc[2][4];
  #pragma unroll
  for (int i=0;i<2;i++)
    #pragma unroll
    for (int j=0;j<4;j++) acc[i][j] = (f32x4){0,0,0,0};

  const int NT = K >> 6;
  stage(0, 0);
  __syncthreads();                 // compiler drains vmcnt before barrier
  int cur = 0;
  for (int kt = 0; kt < NT; ++kt){
    if (kt+1 < NT) stage(cur^1, (kt+1)<<6);
    const unsigned short* pa = &ls[cur][0][0];
    const unsigned short* pb = &ls[cur][1][0];
    #pragma unroll
    for (int ks=0; ks<2; ++ks){
      short8 af[2], bf[4];
      #pragma unroll
      for (int i=0;i<2;i++){
        int ra = wr + i*16 + lr;
        af[i] = *(const short8*)(pa + ra*64 + ((((ks<<2)+lg) ^ (ra&7))<<3));
      }
      #pragma unroll
      for (int j=0;j<4;j++){
        int rb = wc + j*16 + lr;
        bf[j] = *(const short8*)(pb + rb*64 + ((((ks<<2)+lg) ^ (rb&7))<<3));
      }
      #pragma unroll
      for (int i=0;i<2;i++)
        #pragma unroll
        for (int j=0;j<4;j++)
          acc[i][j] = MFMA(af[i], bf[j], acc[i][j]);
    }
    __syncthreads();               // drains this iter's prefetch too
    cur ^= 1;
  }

  #pragma unroll
  for (int i=0;i<2;i++){
    #pragma unroll
    for (int j=0;j<4;j++){
      #pragma unroll
      for (int r=0;r<4;r++){
        int row = m0 + wr + i*16 + lg*4 + r;
        int col = n0 + wc + j*16 + lr;
        float v = acc[i][j][r];
        if (EPI == 1){
          float sw = v / (1.f + __expf(-v));
          Cb[(size_t)row*N + col] = f2b(sw + b2f(radd[(size_t)row*N + col]));
        } else {
          Cf[(size_t)row*N + col] = v;
        }
      }
    }
  }
}

extern "C" void kernel_launch(void* const* d_in, const int* in_sizes, int n_in,
                              void* d_out, int out_size, void* d_ws, size_t ws_size,
                              hipStream_t stream)
{
  (void)in_sizes; (void)n_in; (void)out_size; (void)ws_size;
  const float* x   = (const float*)d_in[0];
  const float* Wq  = (const float*)d_in[1];
  const float* Wk  = (const float*)d_in[2];
  const float* Wv  = (const float*)d_in[3];
  const float* W1  = (const float*)d_in[4];
  const float* W2  = (const float*)d_in[5];
  const float* gnw = (const float*)d_in[6];
  const float* gnb = (const float*)d_in[7];
  float* out = (float*)d_out;

  char* wsp = (char*)d_ws;
  size_t off = 0;
  auto alloc = [&](size_t bytes)->void*{
    off = (off + 255) & ~(size_t)255;
    void* p = wsp + off; off += bytes; return p;
  };
  const size_t NTOK = (size_t)BB*SS;  // 4096
  unsigned short* xb  = (unsigned short*)alloc(NTOK*HID*2);
  unsigned short* w1T = (unsigned short*)alloc((size_t)HID*HID*2);
  unsigned short* w2T = (unsigned short*)alloc((size_t)HID*HID*2);
  unsigned short* wqT = (unsigned short*)alloc((size_t)NH*HD*HD*2);
  unsigned short* wkT = (unsigned short*)alloc((size_t)NH*HD*HD*2);
  unsigned short* wvT = (unsigned short*)alloc((size_t)NH*HD*HD*2);
  unsigned short* qb  = (unsigned short*)alloc(NTOK*HID*2);
  unsigned short* kb  = (unsigned short*)alloc(NTOK*HID*2);
  unsigned short* vb  = (unsigned short*)alloc(NTOK*HID*2);
  float*          U   = (float*)alloc((size_t)BB*NH*NCH*HD*HD*4);
  unsigned short* ST  = (unsigned short*)alloc((size_t)BB*NH*NCH*HD*HD*2);
  unsigned short* rtb = (unsigned short*)alloc(NTOK*HID*2);
  unsigned short* opb = (unsigned short*)alloc(NTOK*HID*2);

  k_cvt<<<dim3(1024), dim3(256), 0, stream>>>(x, xb, (int)(NTOK*HID));
  k_wT<<<dim3(32,32,1), dim3(256), 0, stream>>>(W1, w1T, HID, HID);
  k_wT<<<dim3(32,32,1), dim3(256), 0, stream>>>(W2, w2T, HID, HID);
  k_wT<<<dim3(4,4,NH), dim3(256), 0, stream>>>(Wq, wqT, HD, HD);
  k_wT<<<dim3(4,4,NH), dim3(256), 0, stream>>>(Wk, wkT, HD, HD);
  k_wT<<<dim3(4,4,NH), dim3(256), 0, stream>>>(Wv, wvT, HD, HD);

  k_qkv<<<dim3(BB*NH*32), dim3(256), 0, stream>>>(xb, wqT, wkT, wvT, qb, kb, vb);
  k_chunksum<<<dim3(BB*NH*NCH), dim3(256), 0, stream>>>(kb, vb, U);
  k_state<<<dim3(BB*NH*64), dim3(256), 0, stream>>>(U, ST);
  k_ret<<<dim3(BB*NH*NCH), dim3(256), 0, stream>>>(qb, kb, vb, ST, gnw, gnb, rtb);

  k_gemm<1><<<dim3(256), dim3(512), 0, stream>>>(xb,  w1T, rtb, opb, nullptr, (int)NTOK, HID, HID);
  k_gemm<2><<<dim3(256), dim3(512), 0, stream>>>(opb, w2T, nullptr, nullptr, out, (int)NTOK, HID, HID);
}